// Round 1
// baseline (56813.892 us; speedup 1.0000x reference)
//
#include <hip/hip_runtime.h>
#include <hip/hip_bf16.h>
#include <math.h>

#define N_NODES 4000
#define CC 191
#define CP 192
#define NT 3
#define NB 5
#define NS 10
#define EE 12000
#define GG 32
#define THREE_C 573

// ---------------------------------------------------------------- build h
__global__ void k_build_h(const float* __restrict__ xs, const int* __restrict__ xtype,
                          const int* __restrict__ xtok, float* __restrict__ h) {
    int idx = blockIdx.x * 256 + threadIdx.x;
    if (idx >= N_NODES * CP) return;
    int i = idx / CP, c = idx % CP;
    float v = 0.f;
    if (c < 60) {
        v = (xtype[i] == c) ? 1.f : 0.f;
    } else if (c < 189) {
        int tk = xtok[i];
        tk = tk < 0 ? 0 : (tk > 128 ? 128 : tk);
        v = (tk == c - 60) ? 1.f : 0.f;
    } else if (c < CC) {
        v = xs[i * 2 + (c - 189)];
    }
    h[idx] = v;
}

// ------------------------------------------------- pad conv_w -> [150][192][192]
__global__ void k_pad_conv(const float* __restrict__ w, float* __restrict__ wp) {
    long idx = (long)blockIdx.x * 256 + threadIdx.x;
    if (idx >= 150L * 192 * 192) return;
    int b = (int)(idx / (192 * 192));
    int r = (int)((idx / 192) % 192);
    int c = (int)(idx % 192);
    wp[idx] = (r < CC && c < CC) ? w[(long)b * CC * CC + (long)r * CC + c] : 0.f;
}

// ---------------------------------- pad [batches][573][191] -> [batches][573][192]
__global__ void k_pad573(const float* __restrict__ w, float* __restrict__ wp, int batches) {
    long tot = (long)batches * THREE_C * CP;
    long idx = (long)blockIdx.x * 256 + threadIdx.x;
    if (idx >= tot) return;
    int b = (int)(idx / (THREE_C * CP));
    int r = (int)((idx / CP) % THREE_C);
    int c = (int)(idx % CP);
    wp[idx] = (c < CC) ? w[((long)b * THREE_C + r) * CC + c] : 0.f;
}

// --------------------------------------------------------------- CSR build
__global__ void k_edge_count(const int* __restrict__ ei, const int* __restrict__ et,
                             int* __restrict__ cnt) {
    int e = blockIdx.x * 256 + threadIdx.x;
    if (e >= EE) return;
    int d = ei[EE + e];
    int t = et[e];
    atomicAdd(&cnt[t * N_NODES + d], 1);
}

__global__ void k_scan(const int* __restrict__ cnt, int* __restrict__ off, int* __restrict__ fill) {
    const int TOT = NT * N_NODES;          // 12000
    const int CH = (TOT + 255) / 256;      // 47
    __shared__ int ls[256];
    int tid = threadIdx.x;
    int base = tid * CH;
    int s = 0;
    for (int u = 0; u < CH; u++) {
        int idx = base + u;
        if (idx < TOT) s += cnt[idx];
    }
    ls[tid] = s;
    __syncthreads();
    for (int d = 1; d < 256; d <<= 1) {
        int v = 0;
        if (tid >= d) v = ls[tid - d];
        __syncthreads();
        if (tid >= d) ls[tid] += v;
        __syncthreads();
    }
    int run = (tid > 0) ? ls[tid - 1] : 0;
    for (int u = 0; u < CH; u++) {
        int idx = base + u;
        if (idx < TOT) {
            off[idx] = run;
            fill[idx] = run;
            run += cnt[idx];
        }
    }
    if (tid == 255) off[TOT] = run;
}

__global__ void k_edge_fill(const int* __restrict__ ei, const int* __restrict__ et,
                            int* __restrict__ fill, int* __restrict__ csrc) {
    int e = blockIdx.x * 256 + threadIdx.x;
    if (e >= EE) return;
    int srcv = ei[e];
    int d = ei[EE + e];
    int t = et[e];
    int pos = atomicAdd(&fill[t * N_NODES + d], 1);
    csrc[pos] = srcv;
}

// ------------------------------------ F_t[ts][j][k] = sum_q wih[j][q]*wi_s[k][q]
__global__ __launch_bounds__(256) void k_fmat(const float* __restrict__ wih_p,
                                              const float* __restrict__ conv_wp,
                                              float* __restrict__ F_t, int b) {
    int ts = blockIdx.z;           // t*10+s
    int t = ts / NS;
    int j0 = blockIdx.x * 16;
    int k0 = blockIdx.y * 64;
    const float* A = wih_p + (long)(b * 3 + t) * THREE_C * CP;       // [573][192]
    const float* B = conv_wp + ((long)b * 30 + ts) * 192 * 192;      // [192][192]
    __shared__ float As[16 * CP];
    for (int x = threadIdx.x; x < 16 * CP; x += 256) {
        int jj = j0 + x / CP;
        As[x] = (jj < THREE_C) ? A[(long)jj * CP + (x % CP)] : 0.f;
    }
    __syncthreads();
    int nl = threadIdx.x % 64;
    int jg = threadIdx.x / 64;     // 4 groups of 4 j
    int k = k0 + nl;
    const float4* Brow = (const float4*)(B + (long)k * CP);
    float acc0 = 0.f, acc1 = 0.f, acc2 = 0.f, acc3 = 0.f;
    for (int p4 = 0; p4 < CP / 4; p4++) {
        float4 bv = Brow[p4];
        float4 a0 = ((const float4*)(As + (jg * 4 + 0) * CP))[p4];
        float4 a1 = ((const float4*)(As + (jg * 4 + 1) * CP))[p4];
        float4 a2 = ((const float4*)(As + (jg * 4 + 2) * CP))[p4];
        float4 a3 = ((const float4*)(As + (jg * 4 + 3) * CP))[p4];
        acc0 += a0.x * bv.x + a0.y * bv.y + a0.z * bv.z + a0.w * bv.w;
        acc1 += a1.x * bv.x + a1.y * bv.y + a1.z * bv.z + a1.w * bv.w;
        acc2 += a2.x * bv.x + a2.y * bv.y + a2.z * bv.z + a2.w * bv.w;
        acc3 += a3.x * bv.x + a3.y * bv.y + a3.z * bv.z + a3.w * bv.w;
    }
    float accs[4] = {acc0, acc1, acc2, acc3};
    for (int u = 0; u < 4; u++) {
        int j = j0 + jg * 4 + u;
        if (j < THREE_C) F_t[((long)ts * THREE_C + j) * CP + k] = accs[u];
    }
}

// --------------------------------------------------- init x chains from h
__global__ void k_copy3(const float* __restrict__ h, float* __restrict__ X) {
    int idx = blockIdx.x * 256 + threadIdx.x;
    if (idx >= NT * N_NODES * CP) return;
    X[idx] = h[idx % (N_NODES * CP)];
}

// --------------------------------------------------------- the hot kernel
__global__ __launch_bounds__(256) void k_step(const float* __restrict__ Xc, float* __restrict__ Xn,
                                              const float* __restrict__ F_t,
                                              const float* __restrict__ Whh_p,
                                              const float* __restrict__ bih,
                                              const float* __restrict__ bhh,
                                              const int* __restrict__ off,
                                              const int* __restrict__ csrc,
                                              int b, int s) {
    int t = blockIdx.z;
    int i0 = blockIdx.x * 8;
    int jt = blockIdx.y;
    const float* X = Xc + (long)t * N_NODES * CP;
    __shared__ float xs[8 * CP];
    __shared__ float as[8 * CP];
    for (int x = threadIdx.x; x < 8 * CP; x += 256) {
        xs[x] = X[(long)i0 * CP + x];
        as[x] = 0.f;
    }
    __syncthreads();
    {
        int m = threadIdx.x / 32, l = threadIdx.x % 32;
        int node = i0 + m;
        int e0 = off[t * N_NODES + node];
        int e1 = off[t * N_NODES + node + 1];
        for (int e = e0; e < e1; e++) {
            const float* xr = X + (long)csrc[e] * CP;
            #pragma unroll
            for (int kk = 0; kk < CP / 32; kk++)
                as[m * CP + l + kk * 32] += xr[l + kk * 32];
        }
    }
    __syncthreads();
    int m = threadIdx.x / 32, jl = threadIdx.x % 32;
    int j = jt * 32 + jl;
    int je = (j < CC) ? j : (CC - 1);
    const float* Fb = F_t + (long)(t * NS + s) * THREE_C * CP;
    const float* Wb = Whh_p + (long)(b * 3 + t) * THREE_C * CP;
    const float4* fr = (const float4*)(Fb + (long)je * CP);
    const float4* fz = (const float4*)(Fb + (long)(CC + je) * CP);
    const float4* fc = (const float4*)(Fb + (long)(2 * CC + je) * CP);
    const float4* wr = (const float4*)(Wb + (long)je * CP);
    const float4* wz = (const float4*)(Wb + (long)(CC + je) * CP);
    const float4* wc = (const float4*)(Wb + (long)(2 * CC + je) * CP);
    const float4* xv4 = (const float4*)(xs + m * CP);
    const float4* av4 = (const float4*)(as + m * CP);
    float air = 0.f, aiz = 0.f, aic = 0.f, ahr = 0.f, ahz = 0.f, ahc = 0.f;
    #pragma unroll 2
    for (int k4 = 0; k4 < CP / 4; k4++) {
        float4 xv = xv4[k4], av = av4[k4];
        float4 r1 = fr[k4], z1 = fz[k4], c1 = fc[k4];
        float4 r2 = wr[k4], z2 = wz[k4], c2 = wc[k4];
        air += av.x * r1.x + av.y * r1.y + av.z * r1.z + av.w * r1.w;
        aiz += av.x * z1.x + av.y * z1.y + av.z * z1.z + av.w * z1.w;
        aic += av.x * c1.x + av.y * c1.y + av.z * c1.z + av.w * c1.w;
        ahr += xv.x * r2.x + xv.y * r2.y + xv.z * r2.z + xv.w * r2.w;
        ahz += xv.x * z2.x + xv.y * z2.y + xv.z * z2.z + xv.w * z2.w;
        ahc += xv.x * c2.x + xv.y * c2.y + xv.z * c2.z + xv.w * c2.w;
    }
    float outv = 0.f;
    if (j < CC) {
        const float* bi = bih + (b * 3 + t) * THREE_C;
        const float* bh = bhh + (b * 3 + t) * THREE_C;
        float ir = air + bi[j], iz = aiz + bi[CC + j], ic = aic + bi[2 * CC + j];
        float hr = ahr + bh[j], hz = ahz + bh[CC + j], hc = ahc + bh[2 * CC + j];
        float r = 1.f / (1.f + expf(-(ir + hr)));
        float z = 1.f / (1.f + expf(-(iz + hz)));
        float cg = tanhf(ic + r * hc);
        outv = (1.f - z) * cg + z * xs[m * CP + j];
    }
    Xn[(long)t * N_NODES * CP + (long)(i0 + m) * CP + j] = outv;
}

// --------------------------------------------------------- LayerNorm + ReLU
__global__ void k_ln(float* __restrict__ h, const float* __restrict__ X,
                     const float* __restrict__ lnw, const float* __restrict__ lnb, int b) {
    int i = blockIdx.x;
    int c = threadIdx.x;   // 192 threads
    long base = (long)i * CP + c;
    float v = 0.f;
    if (c < CC)
        v = h[base] + X[base] + X[(long)NT * 0 + (long)N_NODES * CP + base] +
            X[2L * N_NODES * CP + base];
    float sv = v;
    for (int o = 32; o > 0; o >>= 1) sv += __shfl_down(sv, o);
    __shared__ float ls[3];
    __shared__ float bc[2];
    if ((threadIdx.x & 63) == 0) ls[threadIdx.x >> 6] = sv;
    __syncthreads();
    if (threadIdx.x == 0) bc[0] = (ls[0] + ls[1] + ls[2]) / (float)CC;
    __syncthreads();
    float mu = bc[0];
    float d = (c < CC) ? (v - mu) : 0.f;
    float s2 = d * d;
    for (int o = 32; o > 0; o >>= 1) s2 += __shfl_down(s2, o);
    __syncthreads();
    if ((threadIdx.x & 63) == 0) ls[threadIdx.x >> 6] = s2;
    __syncthreads();
    if (threadIdx.x == 0) bc[1] = (ls[0] + ls[1] + ls[2]) / (float)CC;
    __syncthreads();
    float var = bc[1];
    float y = 0.f;
    if (c < CC) {
        y = d * rsqrtf(var + 1e-5f) * lnw[b * CC + c] + lnb[b * CC + c];
        y = y > 0.f ? y : 0.f;
    }
    h[base] = y;
}

// --------------------------------------------------------------- pooling
__global__ void k_pool(const float* __restrict__ h, const int* __restrict__ batch,
                       float* __restrict__ hg, float* __restrict__ gcnt) {
    int idx = blockIdx.x * 256 + threadIdx.x;
    if (idx >= N_NODES * CP) return;
    int i = idx / CP, c = idx % CP;
    int g = batch[i];
    if (c < CC) atomicAdd(&hg[g * CP + c], h[idx]);
    if (c == 0) atomicAdd(&gcnt[g], 1.f);
}

__global__ void k_head1(const float* __restrict__ hg, const float* __restrict__ gcnt,
                        const float* __restrict__ w1, const float* __restrict__ b1,
                        float* __restrict__ z1) {
    int g = blockIdx.x;
    int jcol = threadIdx.x;
    if (jcol >= CC) return;
    float inv = 1.f / fmaxf(gcnt[g], 1.f);
    float acc = 0.f;
    for (int k = 0; k < CC; k++) acc += hg[g * CP + k] * inv * w1[k * CC + jcol];
    acc += b1[jcol];
    z1[g * CP + jcol] = fmaxf(acc, 0.f);
}

__global__ void k_head2(const float* __restrict__ z1, const float* __restrict__ w2,
                        const float* __restrict__ b2, float* __restrict__ out) {
    int idx = threadIdx.x;
    if (idx >= GG * 2) return;
    int g = idx / 2, o = idx % 2;
    float acc = 0.f;
    for (int k = 0; k < CC; k++) acc += z1[g * CP + k] * w2[k * 2 + o];
    out[g * 2 + o] = acc + b2[o];
}

// ================================================================ launch
extern "C" void kernel_launch(void* const* d_in, const int* in_sizes, int n_in,
                              void* d_out, int out_size, void* d_ws, size_t ws_size,
                              hipStream_t stream) {
    const float* xs   = (const float*)d_in[0];
    const float* conv = (const float*)d_in[1];
    const float* wih  = (const float*)d_in[2];
    const float* whh  = (const float*)d_in[3];
    const float* bih  = (const float*)d_in[4];
    const float* bhh  = (const float*)d_in[5];
    const float* lnw  = (const float*)d_in[6];
    const float* lnb  = (const float*)d_in[7];
    const float* hw1  = (const float*)d_in[8];
    const float* hb1  = (const float*)d_in[9];
    const float* hw2  = (const float*)d_in[10];
    const float* hb2  = (const float*)d_in[11];
    const int* xtype  = (const int*)d_in[12];
    const int* xtok   = (const int*)d_in[13];
    const int* ei     = (const int*)d_in[14];
    const int* et     = (const int*)d_in[15];
    const int* batch  = (const int*)d_in[16];
    float* out = (float*)d_out;

    char* ws = (char*)d_ws;
    size_t o = 0;
    auto alloc = [&](size_t nbytes) {
        size_t r = o;
        o = (o + nbytes + 255) & ~(size_t)255;
        return r;
    };
    float* X0     = (float*)(ws + alloc((size_t)NT * N_NODES * CP * 4));
    float* X1     = (float*)(ws + alloc((size_t)NT * N_NODES * CP * 4));
    float* h      = (float*)(ws + alloc((size_t)N_NODES * CP * 4));
    float* F_t    = (float*)(ws + alloc((size_t)30 * THREE_C * CP * 4));
    float* wih_p  = (float*)(ws + alloc((size_t)15 * THREE_C * CP * 4));
    float* whh_p  = (float*)(ws + alloc((size_t)15 * THREE_C * CP * 4));
    float* convp  = (float*)(ws + alloc((size_t)150 * 192 * 192 * 4));
    float* hg     = (float*)(ws + alloc((size_t)GG * CP * 4));
    float* gcnt   = (float*)(ws + alloc((size_t)GG * 4));
    float* z1buf  = (float*)(ws + alloc((size_t)GG * CP * 4));
    int* cnt      = (int*)(ws + alloc((size_t)NT * N_NODES * 4));
    int* offb     = (int*)(ws + alloc((size_t)(NT * N_NODES + 1) * 4));
    int* fillb    = (int*)(ws + alloc((size_t)NT * N_NODES * 4));
    int* csrc     = (int*)(ws + alloc((size_t)EE * 4));
    (void)ws_size; (void)n_in; (void)in_sizes; (void)out_size;

    hipMemsetAsync(cnt, 0, (size_t)NT * N_NODES * 4, stream);
    hipMemsetAsync(hg, 0, (size_t)GG * CP * 4, stream);
    hipMemsetAsync(gcnt, 0, (size_t)GG * 4, stream);

    k_build_h<<<(N_NODES * CP + 255) / 256, 256, 0, stream>>>(xs, xtype, xtok, h);
    k_pad_conv<<<(int)((150L * 192 * 192 + 255) / 256), 256, 0, stream>>>(conv, convp);
    k_pad573<<<(int)(((long)15 * THREE_C * CP + 255) / 256), 256, 0, stream>>>(wih, wih_p, 15);
    k_pad573<<<(int)(((long)15 * THREE_C * CP + 255) / 256), 256, 0, stream>>>(whh, whh_p, 15);
    k_edge_count<<<(EE + 255) / 256, 256, 0, stream>>>(ei, et, cnt);
    k_scan<<<1, 256, 0, stream>>>(cnt, offb, fillb);
    k_edge_fill<<<(EE + 255) / 256, 256, 0, stream>>>(ei, et, fillb, csrc);

    for (int b = 0; b < NB; b++) {
        dim3 fg((THREE_C + 15) / 16, CP / 64, 30);
        k_fmat<<<fg, 256, 0, stream>>>(wih_p, convp, F_t, b);
        k_copy3<<<(NT * N_NODES * CP + 255) / 256, 256, 0, stream>>>(h, X0);
        const float* xcur = X0;
        float* xnext = X1;
        for (int s = 0; s < NS; s++) {
            dim3 sg(N_NODES / 8, CP / 32, NT);
            k_step<<<sg, 256, 0, stream>>>(xcur, xnext, F_t, whh_p, bih, bhh,
                                           offb, csrc, b, s);
            const float* tmp = xnext;
            xnext = (float*)xcur;
            xcur = tmp;
        }
        // after 10 steps result is back in X0
        k_ln<<<N_NODES, CP, 0, stream>>>(h, X0, lnw, lnb, b);
    }

    k_pool<<<(N_NODES * CP + 255) / 256, 256, 0, stream>>>(h, batch, hg, gcnt);
    k_head1<<<GG, CP, 0, stream>>>(hg, gcnt, hw1, hb1, z1buf);
    k_head2<<<1, 64, 0, stream>>>(z1buf, hw2, hb2, out);
}

// Round 2
// 8578.267 us; speedup vs baseline: 6.6230x; 6.6230x over previous
//
#include <hip/hip_runtime.h>
#include <hip/hip_bf16.h>
#include <math.h>

#define N_NODES 4000
#define CC 191
#define CP 192
#define NT 3
#define NB 5
#define NS 10
#define EE 12000
#define GG 32
#define THREE_C 573
#define NC (N_NODES * CP)

__device__ __forceinline__ float dot4(float4 a, float4 b) {
    return a.x * b.x + a.y * b.y + a.z * b.z + a.w * b.w;
}

// ---------------------------------------------------------------- build h
__global__ void k_build_h(const float* __restrict__ xs, const int* __restrict__ xtype,
                          const int* __restrict__ xtok, float* __restrict__ h) {
    int idx = blockIdx.x * 256 + threadIdx.x;
    if (idx >= NC) return;
    int i = idx / CP, c = idx % CP;
    float v = 0.f;
    if (c < 60) {
        v = (xtype[i] == c) ? 1.f : 0.f;
    } else if (c < 189) {
        int tk = xtok[i];
        tk = tk < 0 ? 0 : (tk > 128 ? 128 : tk);
        v = (tk == c - 60) ? 1.f : 0.f;
    } else if (c < CC) {
        v = xs[i * 2 + (c - 189)];
    }
    h[idx] = v;
}

// ------------------------------------------------- pad conv_w -> [150][192][192]
__global__ void k_pad_conv(const float* __restrict__ w, float* __restrict__ wp) {
    long idx = (long)blockIdx.x * 256 + threadIdx.x;
    if (idx >= 150L * 192 * 192) return;
    int b = (int)(idx / (192 * 192));
    int r = (int)((idx / 192) % 192);
    int c = (int)(idx % 192);
    wp[idx] = (r < CC && c < CC) ? w[(long)b * CC * CC + (long)r * CC + c] : 0.f;
}

// ---------------------------------- pad [batches][573][191] -> [batches][573][192]
__global__ void k_pad573(const float* __restrict__ w, float* __restrict__ wp, int batches) {
    long tot = (long)batches * THREE_C * CP;
    long idx = (long)blockIdx.x * 256 + threadIdx.x;
    if (idx >= tot) return;
    int b = (int)(idx / (THREE_C * CP));
    int r = (int)((idx / CP) % THREE_C);
    int c = (int)(idx % CP);
    wp[idx] = (c < CC) ? w[((long)b * THREE_C + r) * CC + c] : 0.f;
}

// --------------------------------------------------------------- CSR build
__global__ void k_edge_count(const int* __restrict__ ei, const int* __restrict__ et,
                             int* __restrict__ cnt) {
    int e = blockIdx.x * 256 + threadIdx.x;
    if (e >= EE) return;
    atomicAdd(&cnt[et[e] * N_NODES + ei[EE + e]], 1);
}

__global__ void k_scan(const int* __restrict__ cnt, int* __restrict__ off, int* __restrict__ fill) {
    const int TOT = NT * N_NODES;
    const int CH = (TOT + 255) / 256;
    __shared__ int ls[256];
    int tid = threadIdx.x;
    int base = tid * CH;
    int s = 0;
    for (int u = 0; u < CH; u++) {
        int idx = base + u;
        if (idx < TOT) s += cnt[idx];
    }
    ls[tid] = s;
    __syncthreads();
    for (int d = 1; d < 256; d <<= 1) {
        int v = 0;
        if (tid >= d) v = ls[tid - d];
        __syncthreads();
        if (tid >= d) ls[tid] += v;
        __syncthreads();
    }
    int run = (tid > 0) ? ls[tid - 1] : 0;
    for (int u = 0; u < CH; u++) {
        int idx = base + u;
        if (idx < TOT) {
            off[idx] = run;
            fill[idx] = run;
            run += cnt[idx];
        }
    }
    if (tid == 255) off[TOT] = run;
}

__global__ void k_edge_fill(const int* __restrict__ ei, const int* __restrict__ et,
                            int* __restrict__ fill, int* __restrict__ csrc) {
    int e = blockIdx.x * 256 + threadIdx.x;
    if (e >= EE) return;
    int pos = atomicAdd(&fill[et[e] * N_NODES + ei[EE + e]], 1);
    csrc[pos] = ei[e];
}

// ------------------------------------ F_t[ts][j3][k] = sum_q wih[j3][q]*conv[ts][k][q]
// Tiled GEMM: block = 32 j3-rows x 64 k-cols, K(q)-tiles of 48.
__global__ __launch_bounds__(256) void k_fmat(const float* __restrict__ wih_p,
                                              const float* __restrict__ conv_wp,
                                              float* __restrict__ F_t, int b) {
    int ts = blockIdx.z;
    int t = ts / NS;
    int j30 = blockIdx.x * 32;
    int k0 = blockIdx.y * 64;
    const float* A = wih_p + (long)(b * 3 + t) * THREE_C * CP;     // [573][192]
    const float* B = conv_wp + ((long)b * 30 + ts) * 192 * 192;    // [192][192]
    __shared__ float sA[32 * 52];
    __shared__ float sB[64 * 52];
    int tid = threadIdx.x;
    int tj = tid % 32;     // k-col group
    int tn = tid / 32;     // j3-row group (0..7)
    float acc0[4] = {0, 0, 0, 0}, acc1[4] = {0, 0, 0, 0};
    for (int kb = 0; kb < 4; kb++) {
        int q0 = kb * 48;
        for (int idx = tid; idx < 32 * 12; idx += 256) {
            int row = idx / 12, c4 = idx % 12;
            int j3 = j30 + row; j3 = j3 < THREE_C ? j3 : THREE_C - 1;
            *(float4*)(sA + row * 52 + c4 * 4) = *(const float4*)(A + (long)j3 * CP + q0 + c4 * 4);
        }
        for (int idx = tid; idx < 64 * 12; idx += 256) {
            int row = idx / 12, c4 = idx % 12;
            *(float4*)(sB + row * 52 + c4 * 4) = *(const float4*)(B + (long)(k0 + row) * CP + q0 + c4 * 4);
        }
        __syncthreads();
        #pragma unroll 3
        for (int q4 = 0; q4 < 12; q4++) {
            float4 bv0 = *(const float4*)(sB + tj * 52 + q4 * 4);
            float4 bv1 = *(const float4*)(sB + (tj + 32) * 52 + q4 * 4);
            #pragma unroll
            for (int u = 0; u < 4; u++) {
                float4 av = *(const float4*)(sA + (tn + 8 * u) * 52 + q4 * 4);
                acc0[u] += dot4(av, bv0);
                acc1[u] += dot4(av, bv1);
            }
        }
        __syncthreads();
    }
    #pragma unroll
    for (int u = 0; u < 4; u++) {
        int j3 = j30 + tn + 8 * u;
        if (j3 < THREE_C) {
            F_t[((long)ts * THREE_C + j3) * CP + k0 + tj] = acc0[u];
            F_t[((long)ts * THREE_C + j3) * CP + k0 + tj + 32] = acc1[u];
        }
    }
}

// --------------------------------------------------- init x chains from h
__global__ void k_copy3(const float* __restrict__ h, float* __restrict__ X) {
    int idx = blockIdx.x * 256 + threadIdx.x;
    if (idx >= NT * NC) return;
    X[idx] = h[idx % NC];
}

// --------------------------------------------------- Agg[t][i][k] = sum_e x[src][k]
__global__ void k_agg(const float* __restrict__ Xc, float* __restrict__ Agg,
                      const int* __restrict__ off, const int* __restrict__ csrc) {
    int node = blockIdx.x;
    int t = blockIdx.y;
    int k = threadIdx.x;   // 192 threads
    const float* Xt = Xc + (long)t * NC;
    int e0 = off[t * N_NODES + node];
    int e1 = off[t * N_NODES + node + 1];
    float s = 0.f;
    for (int e = e0; e < e1; e++) s += Xt[(long)csrc[e] * CP + k];
    Agg[((long)t * N_NODES + node) * CP + k] = s;
}

// --------------------------------------------- hot kernel: tiled GEMM + GRU epilogue
// block: 32 nodes x 32 j, 6 gate-matrices; K-tiles of 48.
__global__ __launch_bounds__(256, 3) void k_step(const float* __restrict__ Xc,
                                                 float* __restrict__ Xn,
                                                 const float* __restrict__ Agg,
                                                 const float* __restrict__ F_t,
                                                 const float* __restrict__ Whh_p,
                                                 const float* __restrict__ bih,
                                                 const float* __restrict__ bhh,
                                                 int b, int s) {
    int t = blockIdx.z;
    int i0g = blockIdx.x * 32;
    int j0 = blockIdx.y * 32;
    const float* Xt = Xc + (long)t * NC;
    const float* Ag = Agg + (long)t * NC;
    const float* Fb = F_t + (long)(t * NS + s) * THREE_C * CP;
    const float* Wb = Whh_p + (long)(b * 3 + t) * THREE_C * CP;

    __shared__ float sA[2 * 32 * 52];   // [x | agg][32 rows][48+pad]
    __shared__ float sB[6 * 32 * 52];   // [Fr,Fz,Fc,Wr,Wz,Wc][32 j][48+pad]

    int tid = threadIdx.x;
    int tj = tid % 32;    // j within tile
    int tn = tid / 32;    // node group (0..7), nodes tn+8u

    float ir[4] = {0, 0, 0, 0}, iz[4] = {0, 0, 0, 0}, ic[4] = {0, 0, 0, 0};
    float hr[4] = {0, 0, 0, 0}, hz[4] = {0, 0, 0, 0}, hc[4] = {0, 0, 0, 0};

    for (int kb = 0; kb < 4; kb++) {
        int k0 = kb * 48;
        // stage A: x and agg tiles (2 x 32 x 12 float4)
        for (int idx = tid; idx < 768; idx += 256) {
            int arr = idx / 384;
            int rem = idx % 384;
            int row = rem / 12, c4 = rem % 12;
            const float* src = arr ? (Ag + (long)(i0g + row) * CP)
                                   : (Xt + (long)(i0g + row) * CP);
            *(float4*)(sA + (arr * 32 + row) * 52 + c4 * 4) =
                *(const float4*)(src + k0 + c4 * 4);
        }
        // stage B: 6 x 32 x 12 float4
        for (int idx = tid; idx < 2304; idx += 256) {
            int mat = idx / 384;
            int rem = idx % 384;
            int row = rem / 12, c4 = rem % 12;
            int j = j0 + row; j = j < CC ? j : CC - 1;
            int gate = (mat < 3) ? mat : mat - 3;
            const float* base = (mat < 3) ? Fb : Wb;
            *(float4*)(sB + (mat * 32 + row) * 52 + c4 * 4) =
                *(const float4*)(base + (long)(gate * CC + j) * CP + k0 + c4 * 4);
        }
        __syncthreads();
        #pragma unroll 2
        for (int q4 = 0; q4 < 12; q4++) {
            float4 fr = *(const float4*)(sB + (0 * 32 + tj) * 52 + q4 * 4);
            float4 fz = *(const float4*)(sB + (1 * 32 + tj) * 52 + q4 * 4);
            float4 fc = *(const float4*)(sB + (2 * 32 + tj) * 52 + q4 * 4);
            float4 wr = *(const float4*)(sB + (3 * 32 + tj) * 52 + q4 * 4);
            float4 wz = *(const float4*)(sB + (4 * 32 + tj) * 52 + q4 * 4);
            float4 wc = *(const float4*)(sB + (5 * 32 + tj) * 52 + q4 * 4);
            #pragma unroll
            for (int u = 0; u < 4; u++) {
                float4 ax = *(const float4*)(sA + (tn + 8 * u) * 52 + q4 * 4);
                float4 ag = *(const float4*)(sA + ((32 + tn + 8 * u)) * 52 + q4 * 4);
                ir[u] += dot4(ag, fr);
                iz[u] += dot4(ag, fz);
                ic[u] += dot4(ag, fc);
                hr[u] += dot4(ax, wr);
                hz[u] += dot4(ax, wz);
                hc[u] += dot4(ax, wc);
            }
        }
        __syncthreads();
    }

    int j = j0 + tj;
    bool valid = j < CC;
    int je = valid ? j : CC - 1;
    const float* bi = bih + (b * 3 + t) * THREE_C;
    const float* bh = bhh + (b * 3 + t) * THREE_C;
    float bir = bi[je], biz = bi[CC + je], bic = bi[2 * CC + je];
    float bhr = bh[je], bhz = bh[CC + je], bhc = bh[2 * CC + je];
    float* Xno = Xn + (long)t * NC;
    #pragma unroll
    for (int u = 0; u < 4; u++) {
        int i = i0g + tn + 8 * u;
        float xold = Xt[(long)i * CP + je];
        float rr = 1.f / (1.f + expf(-(ir[u] + bir + hr[u] + bhr)));
        float zz = 1.f / (1.f + expf(-(iz[u] + biz + hz[u] + bhz)));
        float cg = tanhf(ic[u] + bic + rr * (hc[u] + bhc));
        float outv = valid ? ((1.f - zz) * cg + zz * xold) : 0.f;
        Xno[(long)i * CP + j] = outv;
    }
}

// --------------------------------------------------------- LayerNorm + ReLU
__global__ void k_ln(float* __restrict__ h, const float* __restrict__ X,
                     const float* __restrict__ lnw, const float* __restrict__ lnb, int b) {
    int i = blockIdx.x;
    int c = threadIdx.x;   // 192 threads
    long base = (long)i * CP + c;
    float v = 0.f;
    if (c < CC)
        v = h[base] + X[base] + X[(long)NC + base] + X[2L * NC + base];
    float sv = v;
    for (int o = 32; o > 0; o >>= 1) sv += __shfl_down(sv, o);
    __shared__ float ls[3];
    __shared__ float bc[2];
    if ((threadIdx.x & 63) == 0) ls[threadIdx.x >> 6] = sv;
    __syncthreads();
    if (threadIdx.x == 0) bc[0] = (ls[0] + ls[1] + ls[2]) / (float)CC;
    __syncthreads();
    float mu = bc[0];
    float d = (c < CC) ? (v - mu) : 0.f;
    float s2 = d * d;
    for (int o = 32; o > 0; o >>= 1) s2 += __shfl_down(s2, o);
    __syncthreads();
    if ((threadIdx.x & 63) == 0) ls[threadIdx.x >> 6] = s2;
    __syncthreads();
    if (threadIdx.x == 0) bc[1] = (ls[0] + ls[1] + ls[2]) / (float)CC;
    __syncthreads();
    float var = bc[1];
    float y = 0.f;
    if (c < CC) {
        y = d * rsqrtf(var + 1e-5f) * lnw[b * CC + c] + lnb[b * CC + c];
        y = y > 0.f ? y : 0.f;
    }
    h[base] = y;
}

// --------------------------------------------------------------- pooling
__global__ void k_pool(const float* __restrict__ h, const int* __restrict__ batch,
                       float* __restrict__ hg, float* __restrict__ gcnt) {
    int idx = blockIdx.x * 256 + threadIdx.x;
    if (idx >= NC) return;
    int i = idx / CP, c = idx % CP;
    int g = batch[i];
    if (c < CC) atomicAdd(&hg[g * CP + c], h[idx]);
    if (c == 0) atomicAdd(&gcnt[g], 1.f);
}

__global__ void k_head1(const float* __restrict__ hg, const float* __restrict__ gcnt,
                        const float* __restrict__ w1, const float* __restrict__ b1,
                        float* __restrict__ z1) {
    int g = blockIdx.x;
    int jcol = threadIdx.x;
    if (jcol >= CC) return;
    float inv = 1.f / fmaxf(gcnt[g], 1.f);
    float acc = 0.f;
    for (int k = 0; k < CC; k++) acc += hg[g * CP + k] * inv * w1[k * CC + jcol];
    acc += b1[jcol];
    z1[g * CP + jcol] = fmaxf(acc, 0.f);
}

__global__ void k_head2(const float* __restrict__ z1, const float* __restrict__ w2,
                        const float* __restrict__ b2, float* __restrict__ out) {
    int idx = threadIdx.x;
    if (idx >= GG * 2) return;
    int g = idx / 2, o = idx % 2;
    float acc = 0.f;
    for (int k = 0; k < CC; k++) acc += z1[g * CP + k] * w2[k * 2 + o];
    out[g * 2 + o] = acc + b2[o];
}

// ================================================================ launch
extern "C" void kernel_launch(void* const* d_in, const int* in_sizes, int n_in,
                              void* d_out, int out_size, void* d_ws, size_t ws_size,
                              hipStream_t stream) {
    const float* xs   = (const float*)d_in[0];
    const float* conv = (const float*)d_in[1];
    const float* wih  = (const float*)d_in[2];
    const float* whh  = (const float*)d_in[3];
    const float* bih  = (const float*)d_in[4];
    const float* bhh  = (const float*)d_in[5];
    const float* lnw  = (const float*)d_in[6];
    const float* lnb  = (const float*)d_in[7];
    const float* hw1  = (const float*)d_in[8];
    const float* hb1  = (const float*)d_in[9];
    const float* hw2  = (const float*)d_in[10];
    const float* hb2  = (const float*)d_in[11];
    const int* xtype  = (const int*)d_in[12];
    const int* xtok   = (const int*)d_in[13];
    const int* ei     = (const int*)d_in[14];
    const int* et     = (const int*)d_in[15];
    const int* batch  = (const int*)d_in[16];
    float* out = (float*)d_out;

    char* ws = (char*)d_ws;
    size_t o = 0;
    auto alloc = [&](size_t nbytes) {
        size_t r = o;
        o = (o + nbytes + 255) & ~(size_t)255;
        return r;
    };
    float* X0     = (float*)(ws + alloc((size_t)NT * NC * 4));
    float* X1     = (float*)(ws + alloc((size_t)NT * NC * 4));
    float* AggB   = (float*)(ws + alloc((size_t)NT * NC * 4));
    float* h      = (float*)(ws + alloc((size_t)NC * 4));
    float* F_t    = (float*)(ws + alloc((size_t)30 * THREE_C * CP * 4));
    float* wih_p  = (float*)(ws + alloc((size_t)15 * THREE_C * CP * 4));
    float* whh_p  = (float*)(ws + alloc((size_t)15 * THREE_C * CP * 4));
    float* convp  = (float*)(ws + alloc((size_t)150 * 192 * 192 * 4));
    float* hg     = (float*)(ws + alloc((size_t)GG * CP * 4));
    float* gcnt   = (float*)(ws + alloc((size_t)GG * 4));
    float* z1buf  = (float*)(ws + alloc((size_t)GG * CP * 4));
    int* cnt      = (int*)(ws + alloc((size_t)NT * N_NODES * 4));
    int* offb     = (int*)(ws + alloc((size_t)(NT * N_NODES + 1) * 4));
    int* fillb    = (int*)(ws + alloc((size_t)NT * N_NODES * 4));
    int* csrc     = (int*)(ws + alloc((size_t)EE * 4));
    (void)ws_size; (void)n_in; (void)in_sizes; (void)out_size;

    hipMemsetAsync(cnt, 0, (size_t)NT * N_NODES * 4, stream);
    hipMemsetAsync(hg, 0, (size_t)GG * CP * 4, stream);
    hipMemsetAsync(gcnt, 0, (size_t)GG * 4, stream);

    k_build_h<<<(NC + 255) / 256, 256, 0, stream>>>(xs, xtype, xtok, h);
    k_pad_conv<<<(int)((150L * 192 * 192 + 255) / 256), 256, 0, stream>>>(conv, convp);
    k_pad573<<<(int)(((long)15 * THREE_C * CP + 255) / 256), 256, 0, stream>>>(wih, wih_p, 15);
    k_pad573<<<(int)(((long)15 * THREE_C * CP + 255) / 256), 256, 0, stream>>>(whh, whh_p, 15);
    k_edge_count<<<(EE + 255) / 256, 256, 0, stream>>>(ei, et, cnt);
    k_scan<<<1, 256, 0, stream>>>(cnt, offb, fillb);
    k_edge_fill<<<(EE + 255) / 256, 256, 0, stream>>>(ei, et, fillb, csrc);

    for (int b = 0; b < NB; b++) {
        dim3 fg((THREE_C + 31) / 32, 3, 30);
        k_fmat<<<fg, 256, 0, stream>>>(wih_p, convp, F_t, b);
        k_copy3<<<(NT * NC + 255) / 256, 256, 0, stream>>>(h, X0);
        const float* xcur = X0;
        float* xnext = X1;
        for (int s = 0; s < NS; s++) {
            k_agg<<<dim3(N_NODES, NT), CP, 0, stream>>>(xcur, AggB, offb, csrc);
            dim3 sg(N_NODES / 32, CP / 32, NT);
            k_step<<<sg, 256, 0, stream>>>(xcur, xnext, AggB, F_t, whh_p, bih, bhh, b, s);
            const float* tmp = xnext;
            xnext = (float*)xcur;
            xcur = tmp;
        }
        k_ln<<<N_NODES, CP, 0, stream>>>(h, X0, lnw, lnb, b);
    }

    k_pool<<<(NC + 255) / 256, 256, 0, stream>>>(h, batch, hg, gcnt);
    k_head1<<<GG, CP, 0, stream>>>(hg, gcnt, hw1, hb1, z1buf);
    k_head2<<<1, 64, 0, stream>>>(z1buf, hw2, hb2, out);
}

// Round 3
// 3110.505 us; speedup vs baseline: 18.2652x; 2.7578x over previous
//
#include <hip/hip_runtime.h>
#include <math.h>

#define N_NODES 4000
#define CC 191
#define CP 192
#define NT 3
#define NB 5
#define NS 10
#define EE 12000
#define GG 32
#define THREE_C 573
#define NC (N_NODES * CP)
#define NPAD 576          // padded gate-row count (573 -> 576)

typedef __attribute__((ext_vector_type(8))) short short8;
typedef __attribute__((ext_vector_type(4))) float f32x4;

__device__ __forceinline__ unsigned short f2bf(float f) {
    unsigned u = __float_as_uint(f);
    unsigned r = (u + 0x7fffu + ((u >> 16) & 1u)) >> 16;
    return (unsigned short)r;
}
__device__ __forceinline__ float bf2f(unsigned short s) {
    return __uint_as_float(((unsigned)s) << 16);
}
__device__ __forceinline__ float dot4(float4 a, float4 b) {
    return a.x * b.x + a.y * b.y + a.z * b.z + a.w * b.w;
}

// ---------------------------------------------------------------- build h
__global__ void k_build_h(const float* __restrict__ xs, const int* __restrict__ xtype,
                          const int* __restrict__ xtok, float* __restrict__ h) {
    int idx = blockIdx.x * 256 + threadIdx.x;
    if (idx >= NC) return;
    int i = idx / CP, c = idx % CP;
    float v = 0.f;
    if (c < 60) {
        v = (xtype[i] == c) ? 1.f : 0.f;
    } else if (c < 189) {
        int tk = xtok[i];
        tk = tk < 0 ? 0 : (tk > 128 ? 128 : tk);
        v = (tk == c - 60) ? 1.f : 0.f;
    } else if (c < CC) {
        v = xs[i * 2 + (c - 189)];
    }
    h[idx] = v;
}

// ------------------------------------------------- pad conv_w -> [150][192][192]
__global__ void k_pad_conv(const float* __restrict__ w, float* __restrict__ wp) {
    long idx = (long)blockIdx.x * 256 + threadIdx.x;
    if (idx >= 150L * 192 * 192) return;
    int b = (int)(idx / (192 * 192));
    int r = (int)((idx / 192) % 192);
    int c = (int)(idx % 192);
    wp[idx] = (r < CC && c < CC) ? w[(long)b * CC * CC + (long)r * CC + c] : 0.f;
}

// ---------------------------------- pad [batches][573][191] -> [batches][573][192]
__global__ void k_pad573(const float* __restrict__ w, float* __restrict__ wp, int batches) {
    long tot = (long)batches * THREE_C * CP;
    long idx = (long)blockIdx.x * 256 + threadIdx.x;
    if (idx >= tot) return;
    int b = (int)(idx / (THREE_C * CP));
    int r = (int)((idx / CP) % THREE_C);
    int c = (int)(idx % CP);
    wp[idx] = (c < CC) ? w[((long)b * THREE_C + r) * CC + c] : 0.f;
}

// --------------------------------------------------------------- CSR build
__global__ void k_edge_count(const int* __restrict__ ei, const int* __restrict__ et,
                             int* __restrict__ cnt) {
    int e = blockIdx.x * 256 + threadIdx.x;
    if (e >= EE) return;
    atomicAdd(&cnt[et[e] * N_NODES + ei[EE + e]], 1);
}

__global__ void k_scan(const int* __restrict__ cnt, int* __restrict__ off, int* __restrict__ fill) {
    const int TOT = NT * N_NODES;
    const int CH = (TOT + 255) / 256;
    __shared__ int ls[256];
    int tid = threadIdx.x;
    int base = tid * CH;
    int s = 0;
    for (int u = 0; u < CH; u++) {
        int idx = base + u;
        if (idx < TOT) s += cnt[idx];
    }
    ls[tid] = s;
    __syncthreads();
    for (int d = 1; d < 256; d <<= 1) {
        int v = 0;
        if (tid >= d) v = ls[tid - d];
        __syncthreads();
        if (tid >= d) ls[tid] += v;
        __syncthreads();
    }
    int run = (tid > 0) ? ls[tid - 1] : 0;
    for (int u = 0; u < CH; u++) {
        int idx = base + u;
        if (idx < TOT) {
            off[idx] = run;
            fill[idx] = run;
            run += cnt[idx];
        }
    }
    if (tid == 255) off[TOT] = run;
}

__global__ void k_edge_fill(const int* __restrict__ ei, const int* __restrict__ et,
                            int* __restrict__ fill, int* __restrict__ csrc) {
    int e = blockIdx.x * 256 + threadIdx.x;
    if (e >= EE) return;
    int pos = atomicAdd(&fill[et[e] * N_NODES + ei[EE + e]], 1);
    csrc[pos] = ei[e];
}

// ------------------------------------ F_t[ts][j3][k] = sum_q wih[j3][q]*conv[ts][k][q]
__global__ __launch_bounds__(256) void k_fmat(const float* __restrict__ wih_p,
                                              const float* __restrict__ conv_wp,
                                              float* __restrict__ F_t, int b) {
    int ts = blockIdx.z;
    int t = ts / NS;
    int j30 = blockIdx.x * 32;
    int k0 = blockIdx.y * 64;
    const float* A = wih_p + (long)(b * 3 + t) * THREE_C * CP;
    const float* B = conv_wp + ((long)b * 30 + ts) * 192 * 192;
    __shared__ float sA[32 * 52];
    __shared__ float sB[64 * 52];
    int tid = threadIdx.x;
    int tj = tid % 32;
    int tn = tid / 32;
    float acc0[4] = {0, 0, 0, 0}, acc1[4] = {0, 0, 0, 0};
    for (int kb = 0; kb < 4; kb++) {
        int q0 = kb * 48;
        for (int idx = tid; idx < 32 * 12; idx += 256) {
            int row = idx / 12, c4 = idx % 12;
            int j3 = j30 + row; j3 = j3 < THREE_C ? j3 : THREE_C - 1;
            *(float4*)(sA + row * 52 + c4 * 4) = *(const float4*)(A + (long)j3 * CP + q0 + c4 * 4);
        }
        for (int idx = tid; idx < 64 * 12; idx += 256) {
            int row = idx / 12, c4 = idx % 12;
            *(float4*)(sB + row * 52 + c4 * 4) = *(const float4*)(B + (long)(k0 + row) * CP + q0 + c4 * 4);
        }
        __syncthreads();
        #pragma unroll 3
        for (int q4 = 0; q4 < 12; q4++) {
            float4 bv0 = *(const float4*)(sB + tj * 52 + q4 * 4);
            float4 bv1 = *(const float4*)(sB + (tj + 32) * 52 + q4 * 4);
            #pragma unroll
            for (int u = 0; u < 4; u++) {
                float4 av = *(const float4*)(sA + (tn + 8 * u) * 52 + q4 * 4);
                acc0[u] += dot4(av, bv0);
                acc1[u] += dot4(av, bv1);
            }
        }
        __syncthreads();
    }
    #pragma unroll
    for (int u = 0; u < 4; u++) {
        int j3 = j30 + tn + 8 * u;
        if (j3 < THREE_C) {
            F_t[((long)ts * THREE_C + j3) * CP + k0 + tj] = acc0[u];
            F_t[((long)ts * THREE_C + j3) * CP + k0 + tj + 32] = acc1[u];
        }
    }
}

// ------------------- convert F_t fp32 -> FH/FL bf16 [30][576][192], rows permuted p=3j+g
__global__ void k_convF(const float* __restrict__ F_t, unsigned short* __restrict__ FH,
                        unsigned short* __restrict__ FL) {
    long idx = (long)blockIdx.x * 256 + threadIdx.x;
    if (idx >= 30L * NPAD * CP) return;
    int k = (int)(idx % CP);
    int p = (int)((idx / CP) % NPAD);
    int ts = (int)(idx / ((long)NPAD * CP));
    float v = 0.f;
    if (p < THREE_C) {
        int j = p / 3, g = p % 3;
        v = F_t[((long)ts * THREE_C + g * CC + j) * CP + k];
    }
    unsigned short hi = f2bf(v);
    FH[idx] = hi;
    FL[idx] = f2bf(v - bf2f(hi));
}

// ------------------- convert whh_p fp32 -> WH/WL bf16 [3][576][192], rows permuted
__global__ void k_convW(const float* __restrict__ whh_p, unsigned short* __restrict__ WH,
                        unsigned short* __restrict__ WL, int b) {
    long idx = (long)blockIdx.x * 256 + threadIdx.x;
    if (idx >= 3L * NPAD * CP) return;
    int k = (int)(idx % CP);
    int p = (int)((idx / CP) % NPAD);
    int t = (int)(idx / ((long)NPAD * CP));
    float v = 0.f;
    if (p < THREE_C) {
        int j = p / 3, g = p % 3;
        v = whh_p[((long)(b * 3 + t) * THREE_C + g * CC + j) * CP + k];
    }
    unsigned short hi = f2bf(v);
    WH[idx] = hi;
    WL[idx] = f2bf(v - bf2f(hi));
}

// ------------------- h fp32 -> X0 hi/lo bf16 for the 3 type-chains
__global__ void k_split3(const float* __restrict__ h, unsigned short* __restrict__ XH,
                         unsigned short* __restrict__ XL) {
    int idx = blockIdx.x * 256 + threadIdx.x;
    if (idx >= NC) return;
    float f = h[idx];
    unsigned short hi = f2bf(f);
    unsigned short lo = f2bf(f - bf2f(hi));
    #pragma unroll
    for (int t = 0; t < NT; t++) {
        XH[(long)t * NC + idx] = hi;
        XL[(long)t * NC + idx] = lo;
    }
}

// ------------------- Agg hi/lo from X hi/lo via CSR gather
__global__ void k_agg(const unsigned short* __restrict__ XH, const unsigned short* __restrict__ XL,
                      unsigned short* __restrict__ AH, unsigned short* __restrict__ AL,
                      const int* __restrict__ off, const int* __restrict__ csrc) {
    int node = blockIdx.x;
    int t = blockIdx.y;
    int k = threadIdx.x;   // 192
    const unsigned short* Xh = XH + (long)t * NC;
    const unsigned short* Xl = XL + (long)t * NC;
    int e0 = off[t * N_NODES + node];
    int e1 = off[t * N_NODES + node + 1];
    float s = 0.f;
    for (int e = e0; e < e1; e++) {
        long base = (long)csrc[e] * CP + k;
        s += bf2f(Xh[base]) + bf2f(Xl[base]);
    }
    unsigned short hi = f2bf(s);
    long o = ((long)t * N_NODES + node) * CP + k;
    AH[o] = hi;
    AL[o] = f2bf(s - bf2f(hi));
}

// =================== hot kernel: dual MFMA GEMM (GI, GH) + fused GRU epilogue
// tile: 128 nodes x 96 gate-rows; K' = 576 (compensated bf16 split), k-step 32.
__global__ __launch_bounds__(256, 2) void k_step(
        const unsigned short* __restrict__ XcH, const unsigned short* __restrict__ XcL,
        const unsigned short* __restrict__ AH, const unsigned short* __restrict__ AL,
        const unsigned short* __restrict__ FH, const unsigned short* __restrict__ FL,
        const unsigned short* __restrict__ WH, const unsigned short* __restrict__ WL,
        const float* __restrict__ bih, const float* __restrict__ bhh,
        unsigned short* __restrict__ XnH, unsigned short* __restrict__ XnL,
        int b, int s) {
    const int t = blockIdx.z;
    const int ts = t * NS + s;
    const int M0 = blockIdx.x * 128;
    const int N0 = blockIdx.y * 96;

    __shared__ __align__(16) char smem[35840];
    unsigned short* sX = (unsigned short*)smem;   // 128*40
    unsigned short* sG = sX + 5120;               // 128*40
    unsigned short* sF = sG + 5120;               // 96*40
    unsigned short* sW = sF + 3840;               // 96*40

    const int tid = threadIdx.x;
    const int lane = tid & 63;
    const int wave = tid >> 6;
    const int wm = wave & 1;      // M-half (64)
    const int wn = wave >> 1;     // N-half (48)
    const int l15 = lane & 15;
    const int kb = lane >> 4;

    f32x4 accGI[4][3], accGH[4][3];
    #pragma unroll
    for (int mi = 0; mi < 4; mi++)
        #pragma unroll
        for (int nj = 0; nj < 3; nj++) {
            accGI[mi][nj] = (f32x4){0.f, 0.f, 0.f, 0.f};
            accGH[mi][nj] = (f32x4){0.f, 0.f, 0.f, 0.f};
        }

    for (int ks = 0; ks < 18; ks++) {
        int ako, bko;
        const unsigned short *Xs, *Gs, *Fs, *Ws;
        if (ks < 6)       { ako = ks * 32;        Xs = XcH; Gs = AH; bko = ks * 32;        Fs = FH; Ws = WH; }
        else if (ks < 12) { ako = (ks - 6) * 32;  Xs = XcL; Gs = AL; bko = (ks - 6) * 32;  Fs = FH; Ws = WH; }
        else              { ako = (ks - 12) * 32; Xs = XcH; Gs = AH; bko = (ks - 12) * 32; Fs = FL; Ws = WL; }

        __syncthreads();
        #pragma unroll
        for (int it = 0; it < 2; it++) {
            int idx = tid + it * 256;          // < 512
            int row = idx >> 2, q = idx & 3;
            int node = M0 + row; node = node < N_NODES ? node : N_NODES - 1;
            size_t go = (size_t)(t * N_NODES + node) * CP + ako + q * 8;
            *(uint4*)(sX + row * 40 + q * 8) = *(const uint4*)(Xs + go);
            *(uint4*)(sG + row * 40 + q * 8) = *(const uint4*)(Gs + go);
        }
        {
            int idx = tid;
            if (idx < 384) {
                int row = idx >> 2, q = idx & 3;
                size_t fo = (size_t)(ts * NPAD + N0 + row) * CP + bko + q * 8;
                size_t wo = (size_t)(t * NPAD + N0 + row) * CP + bko + q * 8;
                *(uint4*)(sF + row * 40 + q * 8) = *(const uint4*)(Fs + fo);
                *(uint4*)(sW + row * 40 + q * 8) = *(const uint4*)(Ws + wo);
            }
            idx = tid + 256;
            if (idx < 384) {
                int row = idx >> 2, q = idx & 3;
                size_t fo = (size_t)(ts * NPAD + N0 + row) * CP + bko + q * 8;
                size_t wo = (size_t)(t * NPAD + N0 + row) * CP + bko + q * 8;
                *(uint4*)(sF + row * 40 + q * 8) = *(const uint4*)(Fs + fo);
                *(uint4*)(sW + row * 40 + q * 8) = *(const uint4*)(Ws + wo);
            }
        }
        __syncthreads();

        short8 xa[4], ga[4], fb[3], wb[3];
        #pragma unroll
        for (int mi = 0; mi < 4; mi++) {
            int r = wm * 64 + mi * 16 + l15;
            xa[mi] = *(const short8*)(sX + r * 40 + kb * 8);
            ga[mi] = *(const short8*)(sG + r * 40 + kb * 8);
        }
        #pragma unroll
        for (int nj = 0; nj < 3; nj++) {
            int r = wn * 48 + nj * 16 + l15;
            fb[nj] = *(const short8*)(sF + r * 40 + kb * 8);
            wb[nj] = *(const short8*)(sW + r * 40 + kb * 8);
        }
        #pragma unroll
        for (int mi = 0; mi < 4; mi++)
            #pragma unroll
            for (int nj = 0; nj < 3; nj++) {
                accGI[mi][nj] = __builtin_amdgcn_mfma_f32_16x16x32_bf16(
                    ga[mi], fb[nj], accGI[mi][nj], 0, 0, 0);
                accGH[mi][nj] = __builtin_amdgcn_mfma_f32_16x16x32_bf16(
                    xa[mi], wb[nj], accGH[mi][nj], 0, 0, 0);
            }
    }

    // ---------------- GRU epilogue: 4 phases, one wave's 64x48 quadrant each
    float* eGI = (float*)smem;           // 64 x 50
    float* eGH = eGI + 3200;             // 64 x 50
    const int c = tid & 15;              // channel within 16
    const int rg = tid >> 4;             // row group (0..15)
    const int bo = (b * 3 + t) * THREE_C;

    for (int p = 0; p < 4; p++) {
        __syncthreads();
        if (wave == p) {
            #pragma unroll
            for (int mi = 0; mi < 4; mi++)
                #pragma unroll
                for (int nj = 0; nj < 3; nj++)
                    #pragma unroll
                    for (int r = 0; r < 4; r++) {
                        int grow = mi * 16 + kb * 4 + r;
                        int gcol = nj * 16 + l15;
                        eGI[grow * 50 + gcol] = accGI[mi][nj][r];
                        eGH[grow * 50 + gcol] = accGH[mi][nj][r];
                    }
        }
        __syncthreads();
        int pm = p & 1, pn = p >> 1;
        int j = blockIdx.y * 32 + pn * 16 + c;   // absolute channel, <=191
        float bir = 0, biz = 0, bic = 0, bhr = 0, bhz = 0, bhc = 0;
        if (j < CC) {
            bir = bih[bo + j]; biz = bih[bo + CC + j]; bic = bih[bo + 2 * CC + j];
            bhr = bhh[bo + j]; bhz = bhh[bo + CC + j]; bhc = bhh[bo + 2 * CC + j];
        }
        #pragma unroll
        for (int q = 0; q < 4; q++) {
            int lr = rg * 4 + q;
            int node = M0 + pm * 64 + lr;
            if (node >= N_NODES) continue;
            unsigned short oh = 0, ol = 0;
            if (j < CC) {
                float gir = eGI[lr * 50 + 3 * c], giz = eGI[lr * 50 + 3 * c + 1],
                      gic = eGI[lr * 50 + 3 * c + 2];
                float ghr = eGH[lr * 50 + 3 * c], ghz = eGH[lr * 50 + 3 * c + 1],
                      ghc = eGH[lr * 50 + 3 * c + 2];
                size_t xi = (size_t)(t * N_NODES + node) * CP + j;
                float xold = bf2f(XcH[xi]) + bf2f(XcL[xi]);
                float rr = 1.f / (1.f + expf(-(gir + bir + ghr + bhr)));
                float zz = 1.f / (1.f + expf(-(giz + biz + ghz + bhz)));
                float cg = tanhf(gic + bic + rr * (ghc + bhc));
                float outv = (1.f - zz) * cg + zz * xold;
                oh = f2bf(outv);
                ol = f2bf(outv - bf2f(oh));
            }
            size_t oi = (size_t)(t * N_NODES + node) * CP + j;
            XnH[oi] = oh;
            XnL[oi] = ol;
        }
    }
}

// --------------------------------------------------------- LayerNorm + ReLU
__global__ void k_ln(float* __restrict__ h, const unsigned short* __restrict__ XH,
                     const unsigned short* __restrict__ XL,
                     const float* __restrict__ lnw, const float* __restrict__ lnb, int b) {
    int i = blockIdx.x;
    int c = threadIdx.x;   // 192 threads
    long base = (long)i * CP + c;
    float v = 0.f;
    if (c < CC) {
        v = h[base];
        #pragma unroll
        for (int t = 0; t < NT; t++)
            v += bf2f(XH[(long)t * NC + base]) + bf2f(XL[(long)t * NC + base]);
    }
    float sv = v;
    for (int o = 32; o > 0; o >>= 1) sv += __shfl_down(sv, o);
    __shared__ float ls[3];
    __shared__ float bc[2];
    if ((threadIdx.x & 63) == 0) ls[threadIdx.x >> 6] = sv;
    __syncthreads();
    if (threadIdx.x == 0) bc[0] = (ls[0] + ls[1] + ls[2]) / (float)CC;
    __syncthreads();
    float mu = bc[0];
    float d = (c < CC) ? (v - mu) : 0.f;
    float s2 = d * d;
    for (int o = 32; o > 0; o >>= 1) s2 += __shfl_down(s2, o);
    __syncthreads();
    if ((threadIdx.x & 63) == 0) ls[threadIdx.x >> 6] = s2;
    __syncthreads();
    if (threadIdx.x == 0) bc[1] = (ls[0] + ls[1] + ls[2]) / (float)CC;
    __syncthreads();
    float var = bc[1];
    float y = 0.f;
    if (c < CC) {
        y = d * rsqrtf(var + 1e-5f) * lnw[b * CC + c] + lnb[b * CC + c];
        y = y > 0.f ? y : 0.f;
    }
    h[base] = y;
}

// --------------------------------------------------------------- pooling
__global__ void k_pool(const float* __restrict__ h, const int* __restrict__ batch,
                       float* __restrict__ hg, float* __restrict__ gcnt) {
    int idx = blockIdx.x * 256 + threadIdx.x;
    if (idx >= NC) return;
    int i = idx / CP, c = idx % CP;
    int g = batch[i];
    if (c < CC) atomicAdd(&hg[g * CP + c], h[idx]);
    if (c == 0) atomicAdd(&gcnt[g], 1.f);
}

__global__ void k_head1(const float* __restrict__ hg, const float* __restrict__ gcnt,
                        const float* __restrict__ w1, const float* __restrict__ b1,
                        float* __restrict__ z1) {
    int g = blockIdx.x;
    int jcol = threadIdx.x;
    if (jcol >= CC) return;
    float inv = 1.f / fmaxf(gcnt[g], 1.f);
    float acc = 0.f;
    for (int k = 0; k < CC; k++) acc += hg[g * CP + k] * inv * w1[k * CC + jcol];
    acc += b1[jcol];
    z1[g * CP + jcol] = fmaxf(acc, 0.f);
}

__global__ void k_head2(const float* __restrict__ z1, const float* __restrict__ w2,
                        const float* __restrict__ b2, float* __restrict__ out) {
    int idx = threadIdx.x;
    if (idx >= GG * 2) return;
    int g = idx / 2, o = idx % 2;
    float acc = 0.f;
    for (int k = 0; k < CC; k++) acc += z1[g * CP + k] * w2[k * 2 + o];
    out[g * 2 + o] = acc + b2[o];
}

// ================================================================ launch
extern "C" void kernel_launch(void* const* d_in, const int* in_sizes, int n_in,
                              void* d_out, int out_size, void* d_ws, size_t ws_size,
                              hipStream_t stream) {
    const float* xs   = (const float*)d_in[0];
    const float* conv = (const float*)d_in[1];
    const float* wih  = (const float*)d_in[2];
    const float* whh  = (const float*)d_in[3];
    const float* bih  = (const float*)d_in[4];
    const float* bhh  = (const float*)d_in[5];
    const float* lnw  = (const float*)d_in[6];
    const float* lnb  = (const float*)d_in[7];
    const float* hw1  = (const float*)d_in[8];
    const float* hb1  = (const float*)d_in[9];
    const float* hw2  = (const float*)d_in[10];
    const float* hb2  = (const float*)d_in[11];
    const int* xtype  = (const int*)d_in[12];
    const int* xtok   = (const int*)d_in[13];
    const int* ei     = (const int*)d_in[14];
    const int* et     = (const int*)d_in[15];
    const int* batch  = (const int*)d_in[16];
    float* out = (float*)d_out;

    char* ws = (char*)d_ws;
    size_t o = 0;
    auto alloc = [&](size_t nbytes) {
        size_t r = o;
        o = (o + nbytes + 255) & ~(size_t)255;
        return r;
    };
    float* h      = (float*)(ws + alloc((size_t)NC * 4));
    float* F_t    = (float*)(ws + alloc((size_t)30 * THREE_C * CP * 4));
    float* wih_p  = (float*)(ws + alloc((size_t)15 * THREE_C * CP * 4));
    float* whh_p  = (float*)(ws + alloc((size_t)15 * THREE_C * CP * 4));
    float* convp  = (float*)(ws + alloc((size_t)150 * 192 * 192 * 4));
    unsigned short* FH  = (unsigned short*)(ws + alloc((size_t)30 * NPAD * CP * 2));
    unsigned short* FL  = (unsigned short*)(ws + alloc((size_t)30 * NPAD * CP * 2));
    unsigned short* WH  = (unsigned short*)(ws + alloc((size_t)3 * NPAD * CP * 2));
    unsigned short* WL  = (unsigned short*)(ws + alloc((size_t)3 * NPAD * CP * 2));
    unsigned short* XAh = (unsigned short*)(ws + alloc((size_t)NT * NC * 2));
    unsigned short* XAl = (unsigned short*)(ws + alloc((size_t)NT * NC * 2));
    unsigned short* XBh = (unsigned short*)(ws + alloc((size_t)NT * NC * 2));
    unsigned short* XBl = (unsigned short*)(ws + alloc((size_t)NT * NC * 2));
    unsigned short* AggH = (unsigned short*)(ws + alloc((size_t)NT * NC * 2));
    unsigned short* AggL = (unsigned short*)(ws + alloc((size_t)NT * NC * 2));
    float* hg     = (float*)(ws + alloc((size_t)GG * CP * 4));
    float* gcnt   = (float*)(ws + alloc((size_t)GG * 4));
    float* z1buf  = (float*)(ws + alloc((size_t)GG * CP * 4));
    int* cnt      = (int*)(ws + alloc((size_t)NT * N_NODES * 4));
    int* offb     = (int*)(ws + alloc((size_t)(NT * N_NODES + 1) * 4));
    int* fillb    = (int*)(ws + alloc((size_t)NT * N_NODES * 4));
    int* csrc     = (int*)(ws + alloc((size_t)EE * 4));
    (void)ws_size; (void)n_in; (void)in_sizes; (void)out_size;

    hipMemsetAsync(cnt, 0, (size_t)NT * N_NODES * 4, stream);
    hipMemsetAsync(hg, 0, (size_t)GG * CP * 4, stream);
    hipMemsetAsync(gcnt, 0, (size_t)GG * 4, stream);

    k_build_h<<<(NC + 255) / 256, 256, 0, stream>>>(xs, xtype, xtok, h);
    k_pad_conv<<<(int)((150L * 192 * 192 + 255) / 256), 256, 0, stream>>>(conv, convp);
    k_pad573<<<(int)(((long)15 * THREE_C * CP + 255) / 256), 256, 0, stream>>>(wih, wih_p, 15);
    k_pad573<<<(int)(((long)15 * THREE_C * CP + 255) / 256), 256, 0, stream>>>(whh, whh_p, 15);
    k_edge_count<<<(EE + 255) / 256, 256, 0, stream>>>(ei, et, cnt);
    k_scan<<<1, 256, 0, stream>>>(cnt, offb, fillb);
    k_edge_fill<<<(EE + 255) / 256, 256, 0, stream>>>(ei, et, fillb, csrc);

    for (int b = 0; b < NB; b++) {
        dim3 fg((THREE_C + 31) / 32, 3, 30);
        k_fmat<<<fg, 256, 0, stream>>>(wih_p, convp, F_t, b);
        k_convF<<<(int)((30L * NPAD * CP + 255) / 256), 256, 0, stream>>>(F_t, FH, FL);
        k_convW<<<(int)((3L * NPAD * CP + 255) / 256), 256, 0, stream>>>(whh_p, WH, WL, b);
        k_split3<<<(NC + 255) / 256, 256, 0, stream>>>(h, XAh, XAl);
        unsigned short *curH = XAh, *curL = XAl, *nxtH = XBh, *nxtL = XBl;
        for (int s = 0; s < NS; s++) {
            k_agg<<<dim3(N_NODES, NT), CP, 0, stream>>>(curH, curL, AggH, AggL, offb, csrc);
            dim3 sg(32, 6, NT);   // 4096/128 node tiles x 576/96 gate tiles x types
            k_step<<<sg, 256, 0, stream>>>(curH, curL, AggH, AggL, FH, FL, WH, WL,
                                           bih, bhh, nxtH, nxtL, b, s);
            unsigned short* t1 = curH; curH = nxtH; nxtH = t1;
            unsigned short* t2 = curL; curL = nxtL; nxtL = t2;
        }
        // NS even -> final state is back in XAh/XAl
        k_ln<<<N_NODES, CP, 0, stream>>>(h, XAh, XAl, lnw, lnb, b);
    }

    k_pool<<<(NC + 255) / 256, 256, 0, stream>>>(h, batch, hg, gcnt);
    k_head1<<<GG, CP, 0, stream>>>(hg, gcnt, hw1, hb1, z1buf);
    k_head2<<<1, 64, 0, stream>>>(z1buf, hw2, hb2, out);
}